// Round 8
// baseline (610.935 us; speedup 1.0000x reference)
//
#include <hip/hip_runtime.h>
#include <hip/hip_bf16.h>
#include <cstdint>
#include <cstddef>

#define TT 128
#define BBATCH 256
#define FFEAT 76
#define HDIM 64
#define NHEAD 4
#define DKH 16
#define DFF1 256
#define AH1 8
#define NROWS (BBATCH * FFEAT)   // 19456

#define LOG2E 1.4426950408889634f

typedef __attribute__((ext_vector_type(8))) short bf16x8;
typedef __attribute__((ext_vector_type(4))) float f32x4;

__device__ __forceinline__ float fast_sigmoid(float v) {
    float p = __builtin_amdgcn_exp2f(-v * LOG2E);
    return __builtin_amdgcn_rcpf(1.0f + p);
}
__device__ __forceinline__ float fast_tanh(float v) {
    float p = __builtin_amdgcn_exp2f(v * (2.0f * LOG2E));
    return 1.0f - 2.0f * __builtin_amdgcn_rcpf(1.0f + p);
}
__device__ __forceinline__ short f2bf(float x) {
    __hip_bfloat16 h = __float2bfloat16(x);
    return *reinterpret_cast<short*>(&h);
}
__device__ __forceinline__ float bf2f(unsigned short s) {
    return __uint_as_float(((unsigned)s) << 16);
}
__device__ __forceinline__ unsigned pack_bf16(float a, float b) {
    unsigned ua = (unsigned)(unsigned short)f2bf(a);
    unsigned ub = (unsigned)(unsigned short)f2bf(b);
    return ua | (ub << 16);
}

// ---------------------------------------------------------------------------
// Kernel 1: zero-exchange GRU scan with 2-slot store rotation.
// Block = 256 thr = 4 independent waves; wave owns 16 batches x 64 units.
// h stays in registers (A/B reg slots alternate per t) so the global store of
// h_t has a 2-step window before its registers are overwritten -> no vmcnt
// wait on the critical path. x prefetched one step ahead of use.
// ---------------------------------------------------------------------------
__global__ __launch_bounds__(256, 1) void gru_scan_kernel(
    const float* __restrict__ x, const float* __restrict__ w_ih,
    const float* __restrict__ w_hh, const float* __restrict__ b_ih,
    const float* __restrict__ b_hh, const float* __restrict__ Wt,
    const float* __restrict__ Wx, int f_base,
    __hip_bfloat16* __restrict__ hs, float* __restrict__ wtil)
{
    const int f_loc = blockIdx.y;
    const int f     = f_base + f_loc;
    const int bblk  = blockIdx.x * 64;
    const int tid   = threadIdx.x;
    const int wave  = tid >> 6;
    const int lane  = tid & 63;
    const int c     = lane & 15;
    const int q     = lane >> 4;
    const int b0    = bblk + wave * 16;

    __shared__ float x_lds[TT][64];
    __shared__ float wt_s[64][8];
    __shared__ float wx_s[64][8];
    __shared__ short hx[4][16][72];
    __shared__ float q_s[4][16][8];

    for (int i = tid; i < TT * 64; i += 256) {
        int t = i >> 6, b = i & 63;
        x_lds[t][b] = x[((size_t)t * BBATCH + bblk + b) * FFEAT + f];
    }
    for (int i = tid; i < 512; i += 256) {
        ((float*)wt_s)[i] = Wt[(size_t)f * 512 + i];
        ((float*)wx_s)[i] = Wx[(size_t)f * 512 + i];
    }
    __syncthreads();   // the ONLY block barrier

    // A-fragments (static Whh, permuted). Tile nt: gate = nt>>2, tt = nt&3.
    bf16x8 afr[12][2];
    {
        const float* whh_f = w_hh + (size_t)f * 192 * 64;
        #pragma unroll
        for (int nt = 0; nt < 12; ++nt) {
            int gate = nt >> 2, tt = nt & 3;
            int urow = (c >> 2) * 8 + (tt & 1) * 4 + (c & 3) + (tt >> 1) * 32;
            const float* row = whh_f + (size_t)(gate * 64 + urow) * 64;
            #pragma unroll
            for (int kq = 0; kq < 2; ++kq) {
                bf16x8 fr;
                #pragma unroll
                for (int j = 0; j < 8; ++j) fr[j] = f2bf(row[kq * 32 + q * 8 + j]);
                afr[nt][kq] = fr;
            }
        }
    }
    // per-output constants: output slot (tt, r) -> unit u(q,tt,r), batch c
    float wr[4][4], wz[4][4], wn[4][4], bnx[4][4];
    f32x4 biasv[12];
    #pragma unroll
    for (int tt = 0; tt < 4; ++tt) {
        #pragma unroll
        for (int r = 0; r < 4; ++r) {
            int u = q * 8 + (tt & 1) * 4 + r + (tt >> 1) * 32;
            wr[tt][r]  = w_ih[f*192 + u];
            wz[tt][r]  = w_ih[f*192 + 64 + u];
            wn[tt][r]  = w_ih[f*192 + 128 + u];
            bnx[tt][r] = b_ih[f*192 + 128 + u];
            biasv[tt][r]     = b_ih[f*192 + u]      + b_hh[f*192 + u];
            biasv[4 + tt][r] = b_ih[f*192 + 64 + u] + b_hh[f*192 + 64 + u];
            biasv[8 + tt][r] = b_hh[f*192 + 128 + u];
        }
    }

    float hprev[4][4];
    #pragma unroll
    for (int tt = 0; tt < 4; ++tt)
        #pragma unroll
        for (int r = 0; r < 4; ++r) hprev[tt][r] = 0.f;

    bf16x8 hA0 = {0,0,0,0,0,0,0,0}, hA1 = {0,0,0,0,0,0,0,0};  // slot A
    bf16x8 hB0, hB1;                                           // slot B

    short* hs_b = (short*)hs + ((size_t)f_loc * BBATCH + b0 + c) * TT * HDIM;
    float xcur = x_lds[0][wave * 16 + c];

    // step body: MFMA from IN slot, gates, pack into OUT slot, store OUT at t.
#define SCAN_STEP(T, HIN0, HIN1, HOUT0, HOUT1)                                 \
    {                                                                          \
        f32x4 acc[12];                                                         \
        _Pragma("unroll")                                                      \
        for (int nt = 0; nt < 12; ++nt) {                                      \
            f32x4 a0 = __builtin_amdgcn_mfma_f32_16x16x32_bf16(                \
                afr[nt][0], HIN0, biasv[nt], 0, 0, 0);                         \
            acc[nt]  = __builtin_amdgcn_mfma_f32_16x16x32_bf16(                \
                afr[nt][1], HIN1, a0, 0, 0, 0);                                \
        }                                                                      \
        float xnext = x_lds[((T) + 1 < TT) ? (T) + 1 : (TT - 1)][wave*16 + c]; \
        float hn4[4][4];                                                       \
        _Pragma("unroll")                                                      \
        for (int tt = 0; tt < 4; ++tt) {                                       \
            _Pragma("unroll")                                                  \
            for (int r = 0; r < 4; ++r) {                                      \
                float R  = fmaf(xcur, wr[tt][r], acc[tt][r]);                  \
                float Z  = fmaf(xcur, wz[tt][r], acc[4 + tt][r]);              \
                float NX = fmaf(xcur, wn[tt][r], bnx[tt][r]);                  \
                float rg = fast_sigmoid(R);                                    \
                float zg = fast_sigmoid(Z);                                    \
                float ng = fast_tanh(fmaf(rg, acc[8 + tt][r], NX));            \
                float hn = fmaf(zg, hprev[tt][r] - ng, ng);                    \
                hprev[tt][r] = hn;                                             \
                hn4[tt][r] = hn;                                               \
            }                                                                  \
        }                                                                      \
        {                                                                      \
            union { int4 i; bf16x8 v; } u0, u1;                                \
            u0.i.x = pack_bf16(hn4[0][0], hn4[0][1]);                          \
            u0.i.y = pack_bf16(hn4[0][2], hn4[0][3]);                          \
            u0.i.z = pack_bf16(hn4[1][0], hn4[1][1]);                          \
            u0.i.w = pack_bf16(hn4[1][2], hn4[1][3]);                          \
            u1.i.x = pack_bf16(hn4[2][0], hn4[2][1]);                          \
            u1.i.y = pack_bf16(hn4[2][2], hn4[2][3]);                          \
            u1.i.z = pack_bf16(hn4[3][0], hn4[3][1]);                          \
            u1.i.w = pack_bf16(hn4[3][2], hn4[3][3]);                          \
            HOUT0 = u0.v; HOUT1 = u1.v;                                        \
        }                                                                      \
        short* dst = hs_b + (size_t)(T) * HDIM + q * 8;                        \
        *(bf16x8*)dst = HOUT0;                                                 \
        *(bf16x8*)(dst + 32) = HOUT1;                                          \
        xcur = xnext;                                                          \
    }

    #pragma unroll 1
    for (int t = 0; t < TT; t += 2) {
        SCAN_STEP(t,     hA0, hA1, hB0, hB1);   // even: read A, write/store B
        SCAN_STEP(t + 1, hB0, hB1, hA0, hA1);   // odd : read B, write/store A
    }
#undef SCAN_STEP

    // h_127 lives in slot A (last odd step wrote A). Expose for q/wtilde.
    *(bf16x8*)&hx[wave][c][q * 8]      = hA0;
    *(bf16x8*)&hx[wave][c][32 + q * 8] = hA1;

    // q[b][a] = Wt^T h_127
    #pragma unroll
    for (int rr = 0; rr < 2; ++rr) {
        int role = rr * 64 + lane;
        int b = role >> 3, a = role & 7;
        float s = 0.f;
        #pragma unroll 8
        for (int j = 0; j < 64; ++j)
            s = fmaf(bf2f((unsigned short)hx[wave][b][j]), wt_s[j][a], s);
        q_s[wave][b][a] = s;
    }
    // wtilde[b][j] = sum_a Wx[j][a] * q[b][a]
    {
        int b = lane >> 2, jb = (lane & 3) * 16;
        float qreg[8];
        #pragma unroll
        for (int a = 0; a < 8; ++a) qreg[a] = q_s[wave][b][a];
        float* wt_out = wtil + ((size_t)(b0 + b) * FFEAT + f) * HDIM + jb;
        #pragma unroll
        for (int j4 = 0; j4 < 4; ++j4) {
            float4 v;
            #pragma unroll
            for (int jj = 0; jj < 4; ++jj) {
                int j = jb + j4 * 4 + jj;
                float s = 0.f;
                #pragma unroll
                for (int a = 0; a < 8; ++a) s = fmaf(wx_s[j][a], qreg[a], s);
                (&v.x)[jj] = s;
            }
            *(float4*)&wt_out[j4 * 4] = v;
        }
    }
}

// ---------------------------------------------------------------------------
// Kernel 2: time attention, minimal-footprint version. One wave per (b,f).
// No LDS h-staging: pass 1 streams the 16 KB tile (filling L1), pass 2
// re-reads it coalesced through L1. LDS = a_s only (512 B) -> high block
// co-residency; VGPR ~96 -> ~5 waves/SIMD hides the HBM latency.
// ---------------------------------------------------------------------------
__global__ __launch_bounds__(64) void attn2_kernel(
    const __hip_bfloat16* __restrict__ hs, const float* __restrict__ wtil,
    const float* __restrict__ rate, int f_base, float* __restrict__ emb)
{
    const int b     = blockIdx.x;
    const int f_loc = blockIdx.y;
    const int f     = f_base + f_loc;
    const int lane  = threadIdx.x;

    __shared__ float a_s[TT];

    float wreg[64];
    {
        const float4* src = (const float4*)(wtil + ((size_t)b * FFEAT + f) * HDIM);
        #pragma unroll
        for (int i = 0; i < 16; ++i) {
            float4 v = src[i];
            wreg[4*i+0] = v.x; wreg[4*i+1] = v.y; wreg[4*i+2] = v.z; wreg[4*i+3] = v.w;
        }
    }
    const float rs = fast_sigmoid(rate[f]);
    const short* base = (const short*)hs + ((size_t)f_loc * BBATCH + b) * TT * HDIM;

    float e[2];
    #pragma unroll
    for (int half = 0; half < 2; ++half) {
        int t = half * 64 + lane;
        const uint4* row = (const uint4*)(base + (size_t)t * HDIM);
        float dp = 0.f;
        #pragma unroll
        for (int c4 = 0; c4 < 8; ++c4) {
            uint4 u = row[c4];
            unsigned vals[4] = {u.x, u.y, u.z, u.w};
            #pragma unroll
            for (int p = 0; p < 4; ++p) {
                dp = fmaf(__uint_as_float(vals[p] << 16),         wreg[c4*8 + 2*p],     dp);
                dp = fmaf(__uint_as_float(vals[p] & 0xffff0000u), wreg[c4*8 + 2*p + 1], dp);
            }
        }
        float sig = fast_sigmoid(dp);
        float den = rs * (__logf(2.72f + (1.0f - sig)) * (float)(TT - t));
        e[half] = fmaxf(sig / den, 0.0f);
    }
    float m = fmaxf(e[0], e[1]);
    #pragma unroll
    for (int off = 32; off > 0; off >>= 1) m = fmaxf(m, __shfl_xor(m, off, 64));
    float p0 = __builtin_amdgcn_exp2f((e[0] - m) * LOG2E);
    float p1 = __builtin_amdgcn_exp2f((e[1] - m) * LOG2E);
    float s = p0 + p1;
    #pragma unroll
    for (int off = 32; off > 0; off >>= 1) s += __shfl_xor(s, off, 64);
    float inv = __builtin_amdgcn_rcpf(s);
    a_s[lane]      = p0 * inv;
    a_s[lane + 64] = p1 * inv;
    __syncthreads();   // single wave: cheap; orders a_s for pass 2

    // pass 2: lane = unit j; coalesced L1-hot re-read of the tile
    const short* col = base + lane;
    float acc = 0.f;
    #pragma unroll 8
    for (int t = 0; t < TT; ++t)
        acc = fmaf(a_s[t], bf2f(*(const unsigned short*)(col + (size_t)t * HDIM)), acc);
    emb[((size_t)b * FFEAT + f) * HDIM + lane] = acc;
}

// ---------------------------------------------------------------------------
// Tail: tiled GEMM + MHA core + final head (unchanged).
// ---------------------------------------------------------------------------
struct GemmP {
    const float* X;
    const float* W[3];
    const float* B[3];
    const float* R;
    float* Y[3];
    int K;
    int Nfull;
    int act;
};

__global__ __launch_bounds__(256) void gemm_kernel(GemmP A)
{
    __shared__ float xs[64][65];
    __shared__ float ws[64][68];

    const int tid = threadIdx.x;
    const int tx  = tid & 15;
    const int ty  = tid >> 4;
    const int m0  = blockIdx.x * 64;
    const int n0  = blockIdx.y * 64;
    const int z   = blockIdx.z;

    const float* W = A.W[z];
    const float* Bv = A.B[z];
    float* Y = A.Y[z];
    const int K = A.K, Nfull = A.Nfull;

    float acc[4][4];
    #pragma unroll
    for (int i = 0; i < 4; ++i)
        #pragma unroll
        for (int j = 0; j < 4; ++j) acc[i][j] = 0.f;

    for (int kc = 0; kc < K; kc += 64) {
        for (int s = tid; s < 1024; s += 256) {
            int row = s >> 4, c4 = s & 15;
            float4 xv = *(const float4*)&A.X[(size_t)(m0 + row) * K + kc + 4*c4];
            xs[row][4*c4+0] = xv.x; xs[row][4*c4+1] = xv.y;
            xs[row][4*c4+2] = xv.z; xs[row][4*c4+3] = xv.w;
            float4 wv = *(const float4*)&W[(size_t)(kc + row) * Nfull + n0 + 4*c4];
            *(float4*)&ws[row][4*c4] = wv;
        }
        __syncthreads();
        #pragma unroll 16
        for (int k = 0; k < 64; ++k) {
            float a0 = xs[4*ty+0][k], a1 = xs[4*ty+1][k];
            float a2 = xs[4*ty+2][k], a3 = xs[4*ty+3][k];
            float4 wv = *(const float4*)&ws[k][4*tx];
            #pragma unroll
            for (int j = 0; j < 4; ++j) {
                float wj = (&wv.x)[j];
                acc[0][j] = fmaf(a0, wj, acc[0][j]);
                acc[1][j] = fmaf(a1, wj, acc[1][j]);
                acc[2][j] = fmaf(a2, wj, acc[2][j]);
                acc[3][j] = fmaf(a3, wj, acc[3][j]);
            }
        }
        __syncthreads();
    }

    float4 bias = *(const float4*)&Bv[n0 + 4*tx];
    #pragma unroll
    for (int i = 0; i < 4; ++i) {
        int row = m0 + 4*ty + i;
        float4 v;
        v.x = acc[i][0] + bias.x; v.y = acc[i][1] + bias.y;
        v.z = acc[i][2] + bias.z; v.w = acc[i][3] + bias.w;
        if (A.act) {
            v.x = fmaxf(v.x, 0.f); v.y = fmaxf(v.y, 0.f);
            v.z = fmaxf(v.z, 0.f); v.w = fmaxf(v.w, 0.f);
        }
        if (A.R) {
            float4 r4 = *(const float4*)&A.R[(size_t)row * Nfull + n0 + 4*tx];
            v.x += r4.x; v.y += r4.y; v.z += r4.z; v.w += r4.w;
        }
        *(float4*)&Y[(size_t)row * Nfull + n0 + 4*tx] = v;
    }
}

__global__ __launch_bounds__(256) void mha_core_kernel(
    const float* __restrict__ q, const float* __restrict__ k,
    const float* __restrict__ v, float* __restrict__ ctx)
{
    const int b  = blockIdx.x;
    const int hh = blockIdx.y;
    const int tid = threadIdx.x;

    __shared__ float qs[FFEAT][17];
    __shared__ float ks[FFEAT][17];
    __shared__ float vs[FFEAT][17];
    __shared__ float ps[FFEAT][77];

    for (int idx = tid; idx < FFEAT * DKH; idx += 256) {
        int i = idx >> 4, c = idx & 15;
        size_t g = ((size_t)b * FFEAT + i) * HDIM + hh * DKH + c;
        qs[i][c] = q[g]; ks[i][c] = k[g]; vs[i][c] = v[g];
    }
    __syncthreads();

    for (int idx = tid; idx < FFEAT * FFEAT; idx += 256) {
        int i = idx / FFEAT, j = idx % FFEAT;
        float acc = 0.f;
        #pragma unroll
        for (int c = 0; c < DKH; ++c) acc = fmaf(qs[i][c], ks[j][c], acc);
        ps[i][j] = acc * 0.25f;
    }
    __syncthreads();

    if (tid < FFEAT) {
        float mm = ps[tid][0];
        #pragma unroll 4
        for (int j = 1; j < FFEAT; ++j) mm = fmaxf(mm, ps[tid][j]);
        float ss = 0.f;
        #pragma unroll 4
        for (int j = 0; j < FFEAT; ++j) {
            float pv = __builtin_amdgcn_exp2f((ps[tid][j] - mm) * LOG2E);
            ps[tid][j] = pv; ss += pv;
        }
        float inv = 1.0f / ss;
        #pragma unroll 4
        for (int j = 0; j < FFEAT; ++j) ps[tid][j] *= inv;
    }
    __syncthreads();

    for (int idx = tid; idx < FFEAT * DKH; idx += 256) {
        int i = idx >> 4, c = idx & 15;
        float acc = 0.f;
        #pragma unroll 4
        for (int j = 0; j < FFEAT; ++j) acc = fmaf(ps[i][j], vs[j][c], acc);
        ctx[((size_t)b * FFEAT + i) * HDIM + hh * DKH + c] = acc;
    }
}

__global__ __launch_bounds__(128) void final_kernel(
    const float* __restrict__ ctx3, const float* __restrict__ fk,
    const float* __restrict__ fv,
    const float* __restrict__ faq, const float* __restrict__ fabq,
    const float* __restrict__ o0w, const float* __restrict__ o0b,
    const float* __restrict__ o1w, const float* __restrict__ o1b,
    float* __restrict__ out)
{
    const int b = blockIdx.x;
    const int tid = threadIdx.x;

    __shared__ float last[HDIM];
    __shared__ float fqs[HDIM];
    __shared__ float sm[FFEAT];
    __shared__ float vv[HDIM];
    __shared__ float hh[HDIM];
    __shared__ float redm[2], redp[2];

    if (tid < HDIM) last[tid] = ctx3[((size_t)b * FFEAT + FFEAT - 1) * HDIM + tid];
    __syncthreads();
    if (tid < HDIM) {
        float acc = fabq[tid];
        #pragma unroll 8
        for (int j = 0; j < HDIM; ++j) acc = fmaf(last[j], faq[j * HDIM + tid], acc);
        fqs[tid] = acc;
    }
    __syncthreads();

    float e = -3.0e38f;
    if (tid < FFEAT) {
        const float4* kr = (const float4*)&fk[((size_t)b * FFEAT + tid) * HDIM];
        float acc = 0.f;
        #pragma unroll
        for (int c4 = 0; c4 < 16; ++c4) {
            float4 kv = kr[c4];
            acc = fmaf(kv.x, fqs[4*c4+0], acc);
            acc = fmaf(kv.y, fqs[4*c4+1], acc);
            acc = fmaf(kv.z, fqs[4*c4+2], acc);
            acc = fmaf(kv.w, fqs[4*c4+3], acc);
        }
        e = acc;
    }
    float m = e;
    #pragma unroll
    for (int off = 32; off > 0; off >>= 1) m = fmaxf(m, __shfl_xor(m, off, 64));
    if ((tid & 63) == 0) redm[tid >> 6] = m;
    __syncthreads();
    m = fmaxf(redm[0], redm[1]);
    float p = (tid < FFEAT) ? __builtin_amdgcn_exp2f((e - m) * LOG2E) : 0.f;
    float s = p;
    #pragma unroll
    for (int off = 32; off > 0; off >>= 1) s += __shfl_xor(s, off, 64);
    if ((tid & 63) == 0) redp[tid >> 6] = s;
    __syncthreads();
    s = redp[0] + redp[1];
    if (tid < FFEAT) sm[tid] = p / s;
    __syncthreads();

    if (tid < HDIM) {
        float acc = 0.f;
        for (int ff = 0; ff < FFEAT; ++ff)
            acc = fmaf(sm[ff], fv[((size_t)b * FFEAT + ff) * HDIM + tid], acc);
        vv[tid] = acc;
    }
    __syncthreads();
    if (tid < HDIM) {
        float acc = o0b[tid];
        #pragma unroll 8
        for (int j = 0; j < HDIM; ++j) acc = fmaf(vv[j], o0w[j * HDIM + tid], acc);
        hh[tid] = fmaxf(acc, 0.f);
    }
    __syncthreads();
    if (tid < 64) {
        float t = hh[tid] * o1w[tid];
        #pragma unroll
        for (int off = 32; off > 0; off >>= 1) t += __shfl_xor(t, off, 64);
        if (tid == 0) out[b] = fast_sigmoid(t + o1b[0]);
    }
}

__global__ void ws_report_kernel(float* out, int n, float ws_mib) {
    int i = blockIdx.x * blockDim.x + threadIdx.x;
    if (i < n) out[i] = ws_mib;
}

extern "C" void kernel_launch(void* const* d_in, const int* in_sizes, int n_in,
                              void* d_out, int out_size, void* d_ws, size_t ws_size,
                              hipStream_t stream)
{
    const float* x     = (const float*)d_in[0];
    const float* w_ih  = (const float*)d_in[1];
    const float* w_hh  = (const float*)d_in[2];
    const float* b_ih  = (const float*)d_in[3];
    const float* b_hh  = (const float*)d_in[4];
    const float* attWt = (const float*)d_in[5];
    const float* attWx = (const float*)d_in[6];
    const float* attRt = (const float*)d_in[7];
    const float* wq    = (const float*)d_in[8];
    const float* bq    = (const float*)d_in[9];
    const float* wk    = (const float*)d_in[10];
    const float* bk    = (const float*)d_in[11];
    const float* wv    = (const float*)d_in[12];
    const float* bv    = (const float*)d_in[13];
    const float* wo    = (const float*)d_in[14];
    const float* bo    = (const float*)d_in[15];
    const float* w1    = (const float*)d_in[16];
    const float* b1    = (const float*)d_in[17];
    const float* w2    = (const float*)d_in[18];
    const float* b2    = (const float*)d_in[19];
    const float* faq   = (const float*)d_in[20];
    const float* fabq  = (const float*)d_in[21];
    const float* fak   = (const float*)d_in[22];
    const float* fabk  = (const float*)d_in[23];
    const float* fav   = (const float*)d_in[24];
    const float* fabv  = (const float*)d_in[25];
    const float* o0w   = (const float*)d_in[26];
    const float* o0b   = (const float*)d_in[27];
    const float* o1w   = (const float*)d_in[28];
    const float* o1b   = (const float*)d_in[29];
    float* out = (float*)d_out;

    const size_t emb_bytes  = (size_t)NROWS * HDIM * 4;
    const size_t wtil_bytes = (size_t)NROWS * HDIM * 4;
    const size_t R64        = (size_t)NROWS * HDIM;
    const size_t tail_bytes = 12 * R64 * 4;

    const int chunk_opts[6] = {76, 38, 19, 4, 2, 1};
    int FC = 0;
    for (int i = 0; i < 6; ++i) {
        size_t hs_b = (size_t)chunk_opts[i] * BBATCH * TT * HDIM * 2;
        size_t scratch = hs_b > tail_bytes ? hs_b : tail_bytes;
        if (emb_bytes + wtil_bytes + scratch <= ws_size) { FC = chunk_opts[i]; break; }
    }
    if (FC == 0) {
        ws_report_kernel<<<dim3((out_size + 255) / 256), dim3(256), 0, stream>>>(
            out, out_size, (float)((double)ws_size / (1024.0 * 1024.0)));
        return;
    }

    float* emb  = (float*)d_ws;
    float* wtil = (float*)((char*)d_ws + emb_bytes);
    char*  scratch = (char*)d_ws + emb_bytes + wtil_bytes;
    __hip_bfloat16* hs = (__hip_bfloat16*)scratch;

    for (int f0 = 0; f0 < FFEAT; f0 += FC) {
        int fc = (FFEAT - f0 < FC) ? (FFEAT - f0) : FC;
        gru_scan_kernel<<<dim3(4, fc), dim3(256), 0, stream>>>(
            x, w_ih, w_hh, b_ih, b_hh, attWt, attWx, f0, hs, wtil);
        attn2_kernel<<<dim3(BBATCH, fc), dim3(64), 0, stream>>>(
            hs, wtil, attRt, f0, emb);
    }

    float* ts   = (float*)scratch;
    float* q    = ts;
    float* k    = ts + 1*R64;
    float* v    = ts + 2*R64;
    float* ctx  = ts + 3*R64;
    float* ctx2 = ts + 4*R64;
    float* hid  = ts + 5*R64;
    float* ctx3 = ts + 9*R64;
    float* fk   = ts + 10*R64;
    float* fv   = ts + 11*R64;

    const int MB = NROWS / 64;

    {
        GemmP A = { emb, {wq, wk, wv}, {bq, bk, bv}, nullptr, {q, k, v}, 64, 64, 0 };
        gemm_kernel<<<dim3(MB, 1, 3), dim3(256), 0, stream>>>(A);
    }
    mha_core_kernel<<<dim3(BBATCH, NHEAD), dim3(256), 0, stream>>>(q, k, v, ctx);
    {
        GemmP A = { ctx, {wo, nullptr, nullptr}, {bo, nullptr, nullptr}, emb,
                    {ctx2, nullptr, nullptr}, 64, 64, 0 };
        gemm_kernel<<<dim3(MB, 1, 1), dim3(256), 0, stream>>>(A);
    }
    {
        GemmP A = { ctx2, {w1, nullptr, nullptr}, {b1, nullptr, nullptr}, nullptr,
                    {hid, nullptr, nullptr}, 64, 256, 1 };
        gemm_kernel<<<dim3(MB, 4, 1), dim3(256), 0, stream>>>(A);
    }
    {
        GemmP A = { hid, {w2, nullptr, nullptr}, {b2, nullptr, nullptr}, ctx2,
                    {ctx3, nullptr, nullptr}, 256, 64, 0 };
        gemm_kernel<<<dim3(MB, 1, 1), dim3(256), 0, stream>>>(A);
    }
    {
        GemmP A = { ctx3, {fak, fav, nullptr}, {fabk, fabv, nullptr}, nullptr,
                    {fk, fv, nullptr}, 64, 64, 0 };
        gemm_kernel<<<dim3(MB, 1, 2), dim3(256), 0, stream>>>(A);
    }
    final_kernel<<<dim3(BBATCH), dim3(128), 0, stream>>>(
        ctx3, fk, fv, faq, fabq, o0w, o0b, o1w, o1b, out);
}